// Round 3
// baseline (14567.929 us; speedup 1.0000x reference)
//
#include <hip/hip_runtime.h>
#include <cstddef>
#include <cstdint>

// Problem dims (fixed)
#define T_   4096
#define IN_  1024
#define E_   512
#define G4_  2048   // 4*E

// ---------------------------------------------------------------------------
// Generic fp32 tiled GEMM: C[M,N] = A[M,K] @ op(B) (+ bias1[n] + bias2[n])
// BT=0: B is [K,N] row-major.  BT=1: B is [N,K] row-major (C = A @ B^T).
// Tile 128x128, K-chunk 16, 256 threads, 8x8 accum per thread.
// ---------------------------------------------------------------------------
__global__ __launch_bounds__(256) void gemm_kernel(
    const float* __restrict__ A, const float* __restrict__ B, float* __restrict__ C,
    int M, int N, int K, int BT,
    const float* __restrict__ bias1, const float* __restrict__ bias2)
{
    __shared__ float As[16][128];
    __shared__ float Bs[16][132];
    const int tid = threadIdx.x;
    const int bm = blockIdx.y * 128;
    const int bn = blockIdx.x * 128;
    const int tx = tid & 15;
    const int ty = tid >> 4;
    const int lr = tid >> 1;
    const int lc = (tid & 1) * 8;
    const int bkk = tid & 15;
    const int bn0 = (tid >> 4) * 8;

    float acc[8][8];
#pragma unroll
    for (int i = 0; i < 8; ++i)
#pragma unroll
        for (int j = 0; j < 8; ++j) acc[i][j] = 0.f;

    for (int k0 = 0; k0 < K; k0 += 16) {
        float av[8], bv[8];
        {
            const float* ap = A + (size_t)(bm + lr) * K + (k0 + lc);
            *(float4*)&av[0] = *(const float4*)ap;
            *(float4*)&av[4] = *(const float4*)(ap + 4);
        }
        if (BT) {
            const float* bp = B + (size_t)(bn + lr) * K + (k0 + lc);
            *(float4*)&bv[0] = *(const float4*)bp;
            *(float4*)&bv[4] = *(const float4*)(bp + 4);
        } else {
            const float* bp = B + (size_t)(k0 + bkk) * N + (bn + bn0);
            *(float4*)&bv[0] = *(const float4*)bp;
            *(float4*)&bv[4] = *(const float4*)(bp + 4);
        }
        __syncthreads();
#pragma unroll
        for (int i = 0; i < 8; ++i) As[lc + i][lr] = av[i];
        if (BT) {
#pragma unroll
            for (int i = 0; i < 8; ++i) Bs[lc + i][lr] = bv[i];
        } else {
#pragma unroll
            for (int j = 0; j < 8; ++j) Bs[bkk][bn0 + j] = bv[j];
        }
        __syncthreads();
#pragma unroll
        for (int kk = 0; kk < 16; ++kk) {
            float a0[8], b0[8];
            *(float4*)&a0[0] = *(const float4*)&As[kk][ty * 8];
            *(float4*)&a0[4] = *(const float4*)&As[kk][ty * 8 + 4];
            *(float4*)&b0[0] = *(const float4*)&Bs[kk][tx * 8];
            *(float4*)&b0[4] = *(const float4*)&Bs[kk][tx * 8 + 4];
#pragma unroll
            for (int i = 0; i < 8; ++i)
#pragma unroll
                for (int j = 0; j < 8; ++j)
                    acc[i][j] = fmaf(a0[i], b0[j], acc[i][j]);
        }
    }

    float bias[8];
#pragma unroll
    for (int j = 0; j < 8; ++j) bias[j] = 0.f;
    if (bias1) {
#pragma unroll
        for (int j = 0; j < 8; ++j) bias[j] += bias1[bn + tx * 8 + j];
    }
    if (bias2) {
#pragma unroll
        for (int j = 0; j < 8; ++j) bias[j] += bias2[bn + tx * 8 + j];
    }
#pragma unroll
    for (int i = 0; i < 8; ++i) {
        float outv[8];
#pragma unroll
        for (int j = 0; j < 8; ++j) outv[j] = acc[i][j] + bias[j];
        float* cp = C + (size_t)(bm + ty * 8 + i) * N + (bn + tx * 8);
        *(float4*)cp = *(float4*)&outv[0];
        *(float4*)(cp + 4) = *(float4*)&outv[4];
    }
}

// ---------------------------------------------------------------------------
// Row softmax over 4096 columns, in place. One block per row.
// ---------------------------------------------------------------------------
__global__ __launch_bounds__(256) void softmax_kernel(float* __restrict__ S)
{
    __shared__ float red[8];
    float* p = S + (size_t)blockIdx.x * T_;
    const int tid = threadIdx.x;
    const int wid = tid >> 6;
    const int lane = tid & 63;
    float4 v[4];
#pragma unroll
    for (int i = 0; i < 4; ++i) v[i] = ((const float4*)p)[tid + 256 * i];
    float m = -3.0e38f;
#pragma unroll
    for (int i = 0; i < 4; ++i)
        m = fmaxf(m, fmaxf(fmaxf(v[i].x, v[i].y), fmaxf(v[i].z, v[i].w)));
#pragma unroll
    for (int o = 32; o; o >>= 1) m = fmaxf(m, __shfl_xor(m, o));
    if (lane == 0) red[wid] = m;
    __syncthreads();
    m = fmaxf(fmaxf(red[0], red[1]), fmaxf(red[2], red[3]));
    float s = 0.f;
#pragma unroll
    for (int i = 0; i < 4; ++i) {
        v[i].x = __expf(v[i].x - m); v[i].y = __expf(v[i].y - m);
        v[i].z = __expf(v[i].z - m); v[i].w = __expf(v[i].w - m);
        s += v[i].x + v[i].y + v[i].z + v[i].w;
    }
#pragma unroll
    for (int o = 32; o; o >>= 1) s += __shfl_xor(s, o);
    if (lane == 0) red[4 + wid] = s;
    __syncthreads();
    s = red[4] + red[5] + red[6] + red[7];
    const float inv = 1.f / s;
#pragma unroll
    for (int i = 0; i < 4; ++i) {
        v[i].x *= inv; v[i].y *= inv; v[i].z *= inv; v[i].w *= inv;
        ((float4*)p)[tid + 256 * i] = v[i];
    }
}

// u_mod = u * out_vec, elementwise
__global__ __launch_bounds__(256) void umod_kernel(
    const float* __restrict__ u, const float* __restrict__ ov, float* __restrict__ um)
{
    const int i = blockIdx.x * 256 + threadIdx.x;
    float4 a = ((const float4*)u)[i];
    float4 b = ((const float4*)ov)[i];
    float4 c;
    c.x = a.x * b.x; c.y = a.y * b.y; c.z = a.z * b.z; c.w = a.w * b.w;
    ((float4*)um)[i] = c;
}

// ---------------------------------------------------------------------------
// Persistent bidirectional LSTM, v3.
// v2 + (a) combined dual-slot poll: both 8B tagged loads issued back-to-back
// every iteration (independent, concurrently in flight) instead of two
// sequential dependent poll loops -> saves ~1 full agent-load latency/step.
// Re-reading an already-matched slot is safe: no producer can overwrite a
// parity-p slot with step s+1 until every WG (incl. us) has published step s,
// which happens strictly after this poll completes.
// (b) branchless fast gates: tanh(v)=2*sig(2v)-1 shares a single
// __expf + v_rcp across all 4 gate groups; fast tanh for cell output.
// ---------------------------------------------------------------------------
__global__ __launch_bounds__(256) void lstm_kernel(
    const float* __restrict__ whh_f, const float* __restrict__ whh_b,
    const float* __restrict__ xg_f, const float* __restrict__ xg_b,
    float* __restrict__ hf_out, float* __restrict__ hb_out,
    unsigned long long* __restrict__ hbuf)   // [2 dirs][2 parity][512] tagged
{
    __shared__ float sw[16 * 576];     // 36,864 B  (16 rows x 16 chunks x 36)
    __shared__ float sh[2][16 * 36];   //  4,608 B  (double-buffered staged h)

    const int tid  = threadIdx.x;
    const int dir  = blockIdx.x >> 7;
    const int w    = blockIdx.x & 127;
    const int wid  = tid >> 6;          // unit-in-WG 0..3
    const int lane = tid & 63;
    const int g    = lane >> 4;         // gate 0..3 (i,f,g,o)
    const int c    = lane & 15;         // k-chunk 0..15 (32 elems each)
    const int u    = w * 4 + wid;       // global hidden unit 0..511

    const float* whh = dir ? whh_b : whh_f;
    const float* xg  = dir ? xg_b  : xg_f;
    float* hout = dir ? hb_out : hf_out;
    unsigned long long* hb = hbuf + dir * 1024;

    // One-time stage of this WG's 16 gate rows, chunk-padded layout.
    for (int i = tid; i < 16 * 512; i += 256) {
        const int r = i >> 9;          // local row: r = jj*4 + gg
        const int k = i & 511;
        const int gg = r & 3, jj = r >> 2;
        sw[r * 576 + (k >> 5) * 36 + (k & 31)] =
            whh[(size_t)(gg * E_ + w * 4 + jj) * E_ + k];
    }
    for (int i = tid; i < 16 * 36; i += 256) sh[0][i] = 0.f;  // h_init = 0

    const float* wrow = &sw[(wid * 4 + g) * 576 + c * 36];
    float creg = 0.f;
    float xv = xg[(size_t)(dir ? (T_ - 1) : 0) * G4_ + g * E_ + u];
    unsigned int budget = 1u << 23;    // hang-prevention only; never hit healthy

    // gate-math selectors (uniform per lane)
    const float gsc  = (g == 2) ? 2.f : 1.f;    // arg scale
    const float gmul = (g == 2) ? 2.f : 1.f;    // output scale
    const float gadd = (g == 2) ? -1.f : 0.f;   // output offset

    const int e0 = 2 * tid, e1 = 2 * tid + 1;
    const int p0 = (e0 >> 5) * 36 + (e0 & 31);  // e0 even -> p1 = p0+1, 8B-aligned

    for (int s = 0; s < T_; ++s) {
        const int t = dir ? (T_ - 1 - s) : s;

        if (s > 0) {
            const unsigned int tg = (unsigned int)(s - 1);
            const unsigned long long* src = hb + ((s - 1) & 1) * 512;
            unsigned long long v0, v1;
            for (;;) {
                v0 = __hip_atomic_load(src + e0, __ATOMIC_RELAXED, __HIP_MEMORY_SCOPE_AGENT);
                v1 = __hip_atomic_load(src + e1, __ATOMIC_RELAXED, __HIP_MEMORY_SCOPE_AGENT);
                if (((unsigned int)(v0 >> 32) == tg &&
                     (unsigned int)(v1 >> 32) == tg) || !--budget) break;
            }
            float2 hv;
            hv.x = __uint_as_float((unsigned int)v0);
            hv.y = __uint_as_float((unsigned int)v1);
            *(float2*)&sh[s & 1][p0] = hv;
        }
        __syncthreads();   // the ONLY per-step barrier

        // matvec partial: 32 FMAs, both operands b128 from LDS
        const float* hrow = &sh[s & 1][c * 36];
        float sum = 0.f;
#pragma unroll
        for (int k = 0; k < 32; ++k) sum = fmaf(wrow[k], hrow[k], sum);

        // reduce across the 16 chunk-lanes of this gate group
        sum += __shfl_xor(sum, 1);
        sum += __shfl_xor(sum, 2);
        sum += __shfl_xor(sum, 4);
        sum += __shfl_xor(sum, 8);

        // branchless gate: sig for i,f,o; tanh (=2*sig(2x)-1) for g
        const float x = (sum + xv) * gsc;
        const float r = __builtin_amdgcn_rcpf(1.f + __expf(-x));
        const float val = fmaf(r, gmul, gadd);

        // gather the 4 gates of this unit (groups hold identical values)
        const float iv = __shfl(val, c);
        const float fv = __shfl(val, c + 16);
        const float gv = __shfl(val, c + 32);
        const float ov = __shfl(val, c + 48);
        creg = fmaf(fv, creg, iv * gv);       // identical on all 64 lanes
        const float th = fmaf(2.f, __builtin_amdgcn_rcpf(1.f + __expf(-2.f * creg)), -1.f);
        const float h = ov * th;

        if (lane == 0) {
            const unsigned long long pkt =
                ((unsigned long long)(unsigned int)s << 32) |
                (unsigned long long)__float_as_uint(h);
            __hip_atomic_store(hb + (s & 1) * 512 + u, pkt,
                               __ATOMIC_RELAXED, __HIP_MEMORY_SCOPE_AGENT);
            hout[(size_t)t * E_ + u] = h;
        }

        if (s + 1 < T_)
            xv = xg[(size_t)(dir ? (T_ - 2 - s) : (s + 1)) * G4_ + g * E_ + u];
    }
}

// score[t] = dot(hf[t], fw[0:512]) + dot(hb[t], fw[512:1024]) + fb
__global__ __launch_bounds__(256) void final_kernel(
    const float* __restrict__ hf, const float* __restrict__ hb,
    const float* __restrict__ fw, const float* __restrict__ fb,
    float* __restrict__ out)
{
    const int t = blockIdx.x * 4 + (threadIdx.x >> 6);
    const int lane = threadIdx.x & 63;
    float s = 0.f;
#pragma unroll
    for (int i = 0; i < 8; ++i) {
        const int e = lane + 64 * i;
        s += hf[(size_t)t * E_ + e] * fw[e];
    }
#pragma unroll
    for (int i = 0; i < 8; ++i) {
        const int e = lane + 64 * i;
        s += hb[(size_t)t * E_ + e] * fw[E_ + e];
    }
#pragma unroll
    for (int o = 32; o; o >>= 1) s += __shfl_xor(s, o);
    if (lane == 0) out[t] = s + fb[0];
}

// ---------------------------------------------------------------------------
// Workspace layout (floats; 1 MB = 262144 floats). Peak ~96 MB via overlays:
//   a [0,8MB) b [8,16) u [16,24) S [24,88) ov [88,96)
//   um [24,32)  xf [32,64)  xb [64,96)  hf [0,8)  hb [8,16)
//   tagged hbuf @96MB (2048 x 8B = 16KB)
// ---------------------------------------------------------------------------
extern "C" void kernel_launch(void* const* d_in, const int* in_sizes, int n_in,
                              void* d_out, int out_size, void* d_ws, size_t ws_size,
                              hipStream_t stream)
{
    const float* x     = (const float*)d_in[0];
    const float* Amat  = (const float*)d_in[1];
    const float* Bmat  = (const float*)d_in[2];
    const float* Umat  = (const float*)d_in[3];
    const float* wih_f = (const float*)d_in[4];
    const float* whh_f = (const float*)d_in[5];
    const float* bih_f = (const float*)d_in[6];
    const float* bhh_f = (const float*)d_in[7];
    const float* wih_b = (const float*)d_in[8];
    const float* whh_b = (const float*)d_in[9];
    const float* bih_b = (const float*)d_in[10];
    const float* bhh_b = (const float*)d_in[11];
    const float* fw    = (const float*)d_in[12];
    const float* fb    = (const float*)d_in[13];
    float* out = (float*)d_out;
    float* ws = (float*)d_ws;

    const size_t MBf = 262144;
    float* a_  = ws;
    float* b_  = ws + 8 * MBf;
    float* u_  = ws + 16 * MBf;
    float* S_  = ws + 24 * MBf;
    float* ov_ = ws + 88 * MBf;
    float* um_ = ws + 24 * MBf;
    float* xf_ = ws + 32 * MBf;
    float* xb_ = ws + 64 * MBf;
    float* hf_ = ws;
    float* hb_ = ws + 8 * MBf;
    unsigned long long* hbuf_ = (unsigned long long*)(ws + 96 * MBf);

    dim3 blk(256);

    gemm_kernel<<<dim3(4, 32), blk, 0, stream>>>(x, Amat, a_, T_, E_, IN_, 0, nullptr, nullptr);
    gemm_kernel<<<dim3(4, 32), blk, 0, stream>>>(x, Bmat, b_, T_, E_, IN_, 0, nullptr, nullptr);
    gemm_kernel<<<dim3(4, 32), blk, 0, stream>>>(x, Umat, u_, T_, E_, IN_, 0, nullptr, nullptr);
    gemm_kernel<<<dim3(32, 32), blk, 0, stream>>>(u_, a_, S_, T_, T_, E_, 1, nullptr, nullptr);
    softmax_kernel<<<dim3(T_), blk, 0, stream>>>(S_);
    gemm_kernel<<<dim3(4, 32), blk, 0, stream>>>(S_, b_, ov_, T_, E_, T_, 0, nullptr, nullptr);
    umod_kernel<<<dim3(2048), blk, 0, stream>>>(u_, ov_, um_);
    gemm_kernel<<<dim3(16, 32), blk, 0, stream>>>(um_, wih_f, xf_, T_, G4_, E_, 1, bih_f, bhh_f);
    gemm_kernel<<<dim3(16, 32), blk, 0, stream>>>(um_, wih_b, xb_, T_, G4_, E_, 1, bih_b, bhh_b);
    lstm_kernel<<<dim3(256), blk, 0, stream>>>(whh_f, whh_b, xf_, xb_, hf_, hb_, hbuf_);
    final_kernel<<<dim3(1024), blk, 0, stream>>>(hf_, hb_, fw, fb, out);
}

// Round 4
// 10233.248 us; speedup vs baseline: 1.4236x; 1.4236x over previous
//
#include <hip/hip_runtime.h>
#include <cstddef>
#include <cstdint>

// Problem dims (fixed)
#define T_   4096
#define IN_  1024
#define E_   512
#define G4_  2048   // 4*E

// ---------------------------------------------------------------------------
// Generic fp32 tiled GEMM: C[M,N] = A[M,K] @ op(B) (+ bias1[n] + bias2[n])
// BT=0: B is [K,N] row-major.  BT=1: B is [N,K] row-major (C = A @ B^T).
// Tile 128x128, K-chunk 16, 256 threads, 8x8 accum per thread.
// ---------------------------------------------------------------------------
__global__ __launch_bounds__(256) void gemm_kernel(
    const float* __restrict__ A, const float* __restrict__ B, float* __restrict__ C,
    int M, int N, int K, int BT,
    const float* __restrict__ bias1, const float* __restrict__ bias2)
{
    __shared__ float As[16][128];
    __shared__ float Bs[16][132];
    const int tid = threadIdx.x;
    const int bm = blockIdx.y * 128;
    const int bn = blockIdx.x * 128;
    const int tx = tid & 15;
    const int ty = tid >> 4;
    const int lr = tid >> 1;
    const int lc = (tid & 1) * 8;
    const int bkk = tid & 15;
    const int bn0 = (tid >> 4) * 8;

    float acc[8][8];
#pragma unroll
    for (int i = 0; i < 8; ++i)
#pragma unroll
        for (int j = 0; j < 8; ++j) acc[i][j] = 0.f;

    for (int k0 = 0; k0 < K; k0 += 16) {
        float av[8], bv[8];
        {
            const float* ap = A + (size_t)(bm + lr) * K + (k0 + lc);
            *(float4*)&av[0] = *(const float4*)ap;
            *(float4*)&av[4] = *(const float4*)(ap + 4);
        }
        if (BT) {
            const float* bp = B + (size_t)(bn + lr) * K + (k0 + lc);
            *(float4*)&bv[0] = *(const float4*)bp;
            *(float4*)&bv[4] = *(const float4*)(bp + 4);
        } else {
            const float* bp = B + (size_t)(k0 + bkk) * N + (bn + bn0);
            *(float4*)&bv[0] = *(const float4*)bp;
            *(float4*)&bv[4] = *(const float4*)(bp + 4);
        }
        __syncthreads();
#pragma unroll
        for (int i = 0; i < 8; ++i) As[lc + i][lr] = av[i];
        if (BT) {
#pragma unroll
            for (int i = 0; i < 8; ++i) Bs[lc + i][lr] = bv[i];
        } else {
#pragma unroll
            for (int j = 0; j < 8; ++j) Bs[bkk][bn0 + j] = bv[j];
        }
        __syncthreads();
#pragma unroll
        for (int kk = 0; kk < 16; ++kk) {
            float a0[8], b0[8];
            *(float4*)&a0[0] = *(const float4*)&As[kk][ty * 8];
            *(float4*)&a0[4] = *(const float4*)&As[kk][ty * 8 + 4];
            *(float4*)&b0[0] = *(const float4*)&Bs[kk][tx * 8];
            *(float4*)&b0[4] = *(const float4*)&Bs[kk][tx * 8 + 4];
#pragma unroll
            for (int i = 0; i < 8; ++i)
#pragma unroll
                for (int j = 0; j < 8; ++j)
                    acc[i][j] = fmaf(a0[i], b0[j], acc[i][j]);
        }
    }

    float bias[8];
#pragma unroll
    for (int j = 0; j < 8; ++j) bias[j] = 0.f;
    if (bias1) {
#pragma unroll
        for (int j = 0; j < 8; ++j) bias[j] += bias1[bn + tx * 8 + j];
    }
    if (bias2) {
#pragma unroll
        for (int j = 0; j < 8; ++j) bias[j] += bias2[bn + tx * 8 + j];
    }
#pragma unroll
    for (int i = 0; i < 8; ++i) {
        float outv[8];
#pragma unroll
        for (int j = 0; j < 8; ++j) outv[j] = acc[i][j] + bias[j];
        float* cp = C + (size_t)(bm + ty * 8 + i) * N + (bn + tx * 8);
        *(float4*)cp = *(float4*)&outv[0];
        *(float4*)(cp + 4) = *(float4*)&outv[4];
    }
}

// ---------------------------------------------------------------------------
// Row softmax over 4096 columns, in place. One block per row.
// ---------------------------------------------------------------------------
__global__ __launch_bounds__(256) void softmax_kernel(float* __restrict__ S)
{
    __shared__ float red[8];
    float* p = S + (size_t)blockIdx.x * T_;
    const int tid = threadIdx.x;
    const int wid = tid >> 6;
    const int lane = tid & 63;
    float4 v[4];
#pragma unroll
    for (int i = 0; i < 4; ++i) v[i] = ((const float4*)p)[tid + 256 * i];
    float m = -3.0e38f;
#pragma unroll
    for (int i = 0; i < 4; ++i)
        m = fmaxf(m, fmaxf(fmaxf(v[i].x, v[i].y), fmaxf(v[i].z, v[i].w)));
#pragma unroll
    for (int o = 32; o; o >>= 1) m = fmaxf(m, __shfl_xor(m, o));
    if (lane == 0) red[wid] = m;
    __syncthreads();
    m = fmaxf(fmaxf(red[0], red[1]), fmaxf(red[2], red[3]));
    float s = 0.f;
#pragma unroll
    for (int i = 0; i < 4; ++i) {
        v[i].x = __expf(v[i].x - m); v[i].y = __expf(v[i].y - m);
        v[i].z = __expf(v[i].z - m); v[i].w = __expf(v[i].w - m);
        s += v[i].x + v[i].y + v[i].z + v[i].w;
    }
#pragma unroll
    for (int o = 32; o; o >>= 1) s += __shfl_xor(s, o);
    if (lane == 0) red[4 + wid] = s;
    __syncthreads();
    s = red[4] + red[5] + red[6] + red[7];
    const float inv = 1.f / s;
#pragma unroll
    for (int i = 0; i < 4; ++i) {
        v[i].x *= inv; v[i].y *= inv; v[i].z *= inv; v[i].w *= inv;
        ((float4*)p)[tid + 256 * i] = v[i];
    }
}

// u_mod = u * out_vec, elementwise
__global__ __launch_bounds__(256) void umod_kernel(
    const float* __restrict__ u, const float* __restrict__ ov, float* __restrict__ um)
{
    const int i = blockIdx.x * 256 + threadIdx.x;
    float4 a = ((const float4*)u)[i];
    float4 b = ((const float4*)ov)[i];
    float4 c;
    c.x = a.x * b.x; c.y = a.y * b.y; c.z = a.z * b.z; c.w = a.w * b.w;
    ((float4*)um)[i] = c;
}

// ---------------------------------------------------------------------------
// Persistent bidirectional LSTM, v4: poll-traffic reduction (~8x).
//  - 4B slots: (step16<<16) | bf16(h). Exact-match tag; bf16 exchange only
//    (c-state and hout stay fp32). Halves poll bytes + publish footprint.
//  - 128 WGs (64/dir, 8 units/WG, 72KB LDS): halves the number of pollers.
//    Each wave runs 2 unit-iterations of the proven zero-conflict chunk-36
//    matvec (g=lane>>4, c=lane&15; quarter-wave phasing keeps banks clean).
//  - Gathered publish: LDS gather + one coalesced 8-lane 4B store per WG
//    per step (one 32B line access) instead of scattered per-wave stores.
// Deadlock-free with 2 parity buffers: publishing step s requires having
// seen all tags s-1, which sequences after every WG's last read of s-2.
// ---------------------------------------------------------------------------
#define NU_ 8   // hidden units per WG

__global__ __launch_bounds__(256) void lstm_kernel(
    const float* __restrict__ whh_f, const float* __restrict__ whh_b,
    const float* __restrict__ xg_f, const float* __restrict__ xg_b,
    float* __restrict__ hf_out, float* __restrict__ hb_out,
    unsigned int* __restrict__ hbuf)   // [2 dirs][2 parity][512] 4B tagged
{
    __shared__ float sw[32 * 16 * 36];   // 73,728 B: 32 rows x 16 chunks x 36
    __shared__ float sh[16 * 36];        //  2,304 B: staged h (single buffer OK:
                                         //  barrier-2 fences matvec reads)
    __shared__ float sgh[NU_];           // gathered fp32 h

    const int tid  = threadIdx.x;
    const int dir  = blockIdx.x >> 6;    // grid=128: 0..63 fwd, 64..127 bwd
    const int w    = blockIdx.x & 63;
    const int wid  = tid >> 6;           // wave 0..3
    const int lane = tid & 63;
    const int g    = lane >> 4;          // gate 0..3 (i,f,g,o)
    const int c    = lane & 15;          // k-chunk 0..15 (32 elems each)
    const int u0   = w * NU_;            // first global unit of this WG

    const float* whh = dir ? whh_b : whh_f;
    const float* xg  = dir ? xg_b  : xg_f;
    float* hout = dir ? hb_out : hf_out;
    unsigned int* hb = hbuf + dir * 1024;

    // One-time stage of this WG's 32 gate rows (8 units x 4 gates).
    // Local row r = j*4 + gg  (unit j in 0..7, gate gg).
    for (int i = tid; i < 32 * 512; i += 256) {
        const int r = i >> 9, k = i & 511;
        const int j = r >> 2, gg = r & 3;
        sw[(r * 16 + (k >> 5)) * 36 + (k & 31)] =
            whh[(size_t)(gg * E_ + u0 + j) * E_ + k];
    }
    for (int i = tid; i < 16 * 36; i += 256) sh[i] = 0.f;  // h_init = 0

    // wave wid handles units j0 = wid and j1 = wid+4
    const float* wrow0 = &sw[((wid * 4 + g) * 16 + c) * 36];
    const float* wrow1 = &sw[(((wid + 4) * 4 + g) * 16 + c) * 36];
    float creg0 = 0.f, creg1 = 0.f;

    // gate-math selectors (uniform per lane)
    const float gsc  = (g == 2) ? 2.f : 1.f;
    const float gmul = (g == 2) ? 2.f : 1.f;
    const float gadd = (g == 2) ? -1.f : 0.f;

    // Xg prefetch for step 0
    {
        const int t0 = dir ? (T_ - 1) : 0;
        // (only g,unit matter; 16 c-lanes read the same addr -> broadcast)
    }
    float xv0 = xg[(size_t)(dir ? (T_ - 1) : 0) * G4_ + g * E_ + u0 + wid];
    float xv1 = xg[(size_t)(dir ? (T_ - 1) : 0) * G4_ + g * E_ + u0 + wid + 4];

    unsigned int budget = 1u << 23;   // hang guard; never hit when healthy

    const int e0 = 2 * tid;                       // slots 2t, 2t+1
    const int p0 = (e0 >> 5) * 36 + (e0 & 31);    // e0 even -> p1 = p0+1

    for (int s = 0; s < T_; ++s) {
        const int t = dir ? (T_ - 1 - s) : s;

        if (s > 0) {
            const unsigned int tt = (unsigned int)(s - 1) & 0xFFFFu;
            const unsigned long long* src =
                (const unsigned long long*)(hb + ((s - 1) & 1) * 512);
            unsigned long long v;
            for (;;) {
                v = __hip_atomic_load(src + tid, __ATOMIC_RELAXED,
                                      __HIP_MEMORY_SCOPE_AGENT);
                const unsigned int lo = (unsigned int)v;
                const unsigned int hi = (unsigned int)(v >> 32);
                if (((lo >> 16) == tt && (hi >> 16) == tt) || !--budget) break;
            }
            float2 hv;
            hv.x = __uint_as_float((unsigned int)v << 16);          // bf16->f32
            hv.y = __uint_as_float((unsigned int)(v >> 32) << 16);
            *(float2*)&sh[p0] = hv;
        }
        __syncthreads();   // barrier 1: h staged (covers sw staging at s=0)

        // two matvec partials: 32 FMAs each, b128 LDS operands, interleaved
        const float* hrow = &sh[c * 36];
        float s0 = 0.f, s1 = 0.f;
#pragma unroll
        for (int k = 0; k < 32; ++k) {
            const float hk = hrow[k];
            s0 = fmaf(wrow0[k], hk, s0);
            s1 = fmaf(wrow1[k], hk, s1);
        }
        // reduce across the 16 chunk-lanes of this gate group
        s0 += __shfl_xor(s0, 1);  s1 += __shfl_xor(s1, 1);
        s0 += __shfl_xor(s0, 2);  s1 += __shfl_xor(s1, 2);
        s0 += __shfl_xor(s0, 4);  s1 += __shfl_xor(s1, 4);
        s0 += __shfl_xor(s0, 8);  s1 += __shfl_xor(s1, 8);

        // branchless gates: sig for i,f,o; tanh (=2*sig(2x)-1) for g
        const float x0 = (s0 + xv0) * gsc;
        const float x1 = (s1 + xv1) * gsc;
        const float r0 = __builtin_amdgcn_rcpf(1.f + __expf(-x0));
        const float r1 = __builtin_amdgcn_rcpf(1.f + __expf(-x1));
        const float val0 = fmaf(r0, gmul, gadd);
        const float val1 = fmaf(r1, gmul, gadd);

        // gather 4 gates per unit (all lanes compute identical unit values)
        const float iv0 = __shfl(val0, c);
        const float fv0 = __shfl(val0, c + 16);
        const float gv0 = __shfl(val0, c + 32);
        const float ov0 = __shfl(val0, c + 48);
        const float iv1 = __shfl(val1, c);
        const float fv1 = __shfl(val1, c + 16);
        const float gv1 = __shfl(val1, c + 32);
        const float ov1 = __shfl(val1, c + 48);
        creg0 = fmaf(fv0, creg0, iv0 * gv0);
        creg1 = fmaf(fv1, creg1, iv1 * gv1);
        const float th0 = fmaf(2.f, __builtin_amdgcn_rcpf(1.f + __expf(-2.f * creg0)), -1.f);
        const float th1 = fmaf(2.f, __builtin_amdgcn_rcpf(1.f + __expf(-2.f * creg1)), -1.f);
        const float h0 = ov0 * th0;
        const float h1 = ov1 * th1;

        if (lane == 0) sgh[wid] = h0;
        if (lane == 1) sgh[wid + 4] = h1;
        __syncthreads();   // barrier 2: gather complete; also fences sh reads

        if (tid < NU_) {
            const float h = sgh[tid];
            const unsigned int ub = __float_as_uint(h);
            const unsigned int b16 = (ub + 0x7FFFu + ((ub >> 16) & 1u)) >> 16; // RNE
            const unsigned int pkt =
                (((unsigned int)s & 0xFFFFu) << 16) | b16;
            __hip_atomic_store(hb + (s & 1) * 512 + u0 + tid, pkt,
                               __ATOMIC_RELAXED, __HIP_MEMORY_SCOPE_AGENT);
            hout[(size_t)t * E_ + u0 + tid] = h;   // fp32 h for the projection
        }

        if (s + 1 < T_) {
            const int tn = dir ? (T_ - 2 - s) : (s + 1);
            xv0 = xg[(size_t)tn * G4_ + g * E_ + u0 + wid];
            xv1 = xg[(size_t)tn * G4_ + g * E_ + u0 + wid + 4];
        }
    }
}

// score[t] = dot(hf[t], fw[0:512]) + dot(hb[t], fw[512:1024]) + fb
__global__ __launch_bounds__(256) void final_kernel(
    const float* __restrict__ hf, const float* __restrict__ hb,
    const float* __restrict__ fw, const float* __restrict__ fb,
    float* __restrict__ out)
{
    const int t = blockIdx.x * 4 + (threadIdx.x >> 6);
    const int lane = threadIdx.x & 63;
    float s = 0.f;
#pragma unroll
    for (int i = 0; i < 8; ++i) {
        const int e = lane + 64 * i;
        s += hf[(size_t)t * E_ + e] * fw[e];
    }
#pragma unroll
    for (int i = 0; i < 8; ++i) {
        const int e = lane + 64 * i;
        s += hb[(size_t)t * E_ + e] * fw[E_ + e];
    }
#pragma unroll
    for (int o = 32; o; o >>= 1) s += __shfl_xor(s, o);
    if (lane == 0) out[t] = s + fb[0];
}

// ---------------------------------------------------------------------------
// Workspace layout (floats; 1 MB = 262144 floats). Peak ~96 MB via overlays:
//   a [0,8MB) b [8,16) u [16,24) S [24,88) ov [88,96)
//   um [24,32)  xf [32,64)  xb [64,96)  hf [0,8)  hb [8,16)
//   tagged hbuf @96MB (2048 x 4B = 8KB)
// ---------------------------------------------------------------------------
extern "C" void kernel_launch(void* const* d_in, const int* in_sizes, int n_in,
                              void* d_out, int out_size, void* d_ws, size_t ws_size,
                              hipStream_t stream)
{
    const float* x     = (const float*)d_in[0];
    const float* Amat  = (const float*)d_in[1];
    const float* Bmat  = (const float*)d_in[2];
    const float* Umat  = (const float*)d_in[3];
    const float* wih_f = (const float*)d_in[4];
    const float* whh_f = (const float*)d_in[5];
    const float* bih_f = (const float*)d_in[6];
    const float* bhh_f = (const float*)d_in[7];
    const float* wih_b = (const float*)d_in[8];
    const float* whh_b = (const float*)d_in[9];
    const float* bih_b = (const float*)d_in[10];
    const float* bhh_b = (const float*)d_in[11];
    const float* fw    = (const float*)d_in[12];
    const float* fb    = (const float*)d_in[13];
    float* out = (float*)d_out;
    float* ws = (float*)d_ws;

    const size_t MBf = 262144;
    float* a_  = ws;
    float* b_  = ws + 8 * MBf;
    float* u_  = ws + 16 * MBf;
    float* S_  = ws + 24 * MBf;
    float* ov_ = ws + 88 * MBf;
    float* um_ = ws + 24 * MBf;
    float* xf_ = ws + 32 * MBf;
    float* xb_ = ws + 64 * MBf;
    float* hf_ = ws;
    float* hb_ = ws + 8 * MBf;
    unsigned int* hbuf_ = (unsigned int*)(ws + 96 * MBf);

    dim3 blk(256);

    gemm_kernel<<<dim3(4, 32), blk, 0, stream>>>(x, Amat, a_, T_, E_, IN_, 0, nullptr, nullptr);
    gemm_kernel<<<dim3(4, 32), blk, 0, stream>>>(x, Bmat, b_, T_, E_, IN_, 0, nullptr, nullptr);
    gemm_kernel<<<dim3(4, 32), blk, 0, stream>>>(x, Umat, u_, T_, E_, IN_, 0, nullptr, nullptr);
    gemm_kernel<<<dim3(32, 32), blk, 0, stream>>>(u_, a_, S_, T_, T_, E_, 1, nullptr, nullptr);
    softmax_kernel<<<dim3(T_), blk, 0, stream>>>(S_);
    gemm_kernel<<<dim3(4, 32), blk, 0, stream>>>(S_, b_, ov_, T_, E_, T_, 0, nullptr, nullptr);
    umod_kernel<<<dim3(2048), blk, 0, stream>>>(u_, ov_, um_);
    gemm_kernel<<<dim3(16, 32), blk, 0, stream>>>(um_, wih_f, xf_, T_, G4_, E_, 1, bih_f, bhh_f);
    gemm_kernel<<<dim3(16, 32), blk, 0, stream>>>(um_, wih_b, xb_, T_, G4_, E_, 1, bih_b, bhh_b);
    lstm_kernel<<<dim3(128), blk, 0, stream>>>(whh_f, whh_b, xf_, xb_, hf_, hb_, hbuf_);
    final_kernel<<<dim3(1024), blk, 0, stream>>>(hf_, hb_, fw, fb, out);
}

// Round 5
// 9927.701 us; speedup vs baseline: 1.4674x; 1.0308x over previous
//
#include <hip/hip_runtime.h>
#include <cstddef>
#include <cstdint>

// Problem dims (fixed)
#define T_   4096
#define IN_  1024
#define E_   512
#define G4_  2048   // 4*E

// ---------------------------------------------------------------------------
// Generic fp32 tiled GEMM: C[M,N] = A[M,K] @ op(B) (+ bias1[n] + bias2[n])
// BT=0: B is [K,N] row-major.  BT=1: B is [N,K] row-major (C = A @ B^T).
// Tile 128x128, K-chunk 16, 256 threads, 8x8 accum per thread.
// ---------------------------------------------------------------------------
__global__ __launch_bounds__(256) void gemm_kernel(
    const float* __restrict__ A, const float* __restrict__ B, float* __restrict__ C,
    int M, int N, int K, int BT,
    const float* __restrict__ bias1, const float* __restrict__ bias2)
{
    __shared__ float As[16][128];
    __shared__ float Bs[16][132];
    const int tid = threadIdx.x;
    const int bm = blockIdx.y * 128;
    const int bn = blockIdx.x * 128;
    const int tx = tid & 15;
    const int ty = tid >> 4;
    const int lr = tid >> 1;
    const int lc = (tid & 1) * 8;
    const int bkk = tid & 15;
    const int bn0 = (tid >> 4) * 8;

    float acc[8][8];
#pragma unroll
    for (int i = 0; i < 8; ++i)
#pragma unroll
        for (int j = 0; j < 8; ++j) acc[i][j] = 0.f;

    for (int k0 = 0; k0 < K; k0 += 16) {
        float av[8], bv[8];
        {
            const float* ap = A + (size_t)(bm + lr) * K + (k0 + lc);
            *(float4*)&av[0] = *(const float4*)ap;
            *(float4*)&av[4] = *(const float4*)(ap + 4);
        }
        if (BT) {
            const float* bp = B + (size_t)(bn + lr) * K + (k0 + lc);
            *(float4*)&bv[0] = *(const float4*)bp;
            *(float4*)&bv[4] = *(const float4*)(bp + 4);
        } else {
            const float* bp = B + (size_t)(k0 + bkk) * N + (bn + bn0);
            *(float4*)&bv[0] = *(const float4*)bp;
            *(float4*)&bv[4] = *(const float4*)(bp + 4);
        }
        __syncthreads();
#pragma unroll
        for (int i = 0; i < 8; ++i) As[lc + i][lr] = av[i];
        if (BT) {
#pragma unroll
            for (int i = 0; i < 8; ++i) Bs[lc + i][lr] = bv[i];
        } else {
#pragma unroll
            for (int j = 0; j < 8; ++j) Bs[bkk][bn0 + j] = bv[j];
        }
        __syncthreads();
#pragma unroll
        for (int kk = 0; kk < 16; ++kk) {
            float a0[8], b0[8];
            *(float4*)&a0[0] = *(const float4*)&As[kk][ty * 8];
            *(float4*)&a0[4] = *(const float4*)&As[kk][ty * 8 + 4];
            *(float4*)&b0[0] = *(const float4*)&Bs[kk][tx * 8];
            *(float4*)&b0[4] = *(const float4*)&Bs[kk][tx * 8 + 4];
#pragma unroll
            for (int i = 0; i < 8; ++i)
#pragma unroll
                for (int j = 0; j < 8; ++j)
                    acc[i][j] = fmaf(a0[i], b0[j], acc[i][j]);
        }
    }

    float bias[8];
#pragma unroll
    for (int j = 0; j < 8; ++j) bias[j] = 0.f;
    if (bias1) {
#pragma unroll
        for (int j = 0; j < 8; ++j) bias[j] += bias1[bn + tx * 8 + j];
    }
    if (bias2) {
#pragma unroll
        for (int j = 0; j < 8; ++j) bias[j] += bias2[bn + tx * 8 + j];
    }
#pragma unroll
    for (int i = 0; i < 8; ++i) {
        float outv[8];
#pragma unroll
        for (int j = 0; j < 8; ++j) outv[j] = acc[i][j] + bias[j];
        float* cp = C + (size_t)(bm + ty * 8 + i) * N + (bn + tx * 8);
        *(float4*)cp = *(float4*)&outv[0];
        *(float4*)(cp + 4) = *(float4*)&outv[4];
    }
}

// ---------------------------------------------------------------------------
// Row softmax over 4096 columns, in place. One block per row.
// ---------------------------------------------------------------------------
__global__ __launch_bounds__(256) void softmax_kernel(float* __restrict__ S)
{
    __shared__ float red[8];
    float* p = S + (size_t)blockIdx.x * T_;
    const int tid = threadIdx.x;
    const int wid = tid >> 6;
    const int lane = tid & 63;
    float4 v[4];
#pragma unroll
    for (int i = 0; i < 4; ++i) v[i] = ((const float4*)p)[tid + 256 * i];
    float m = -3.0e38f;
#pragma unroll
    for (int i = 0; i < 4; ++i)
        m = fmaxf(m, fmaxf(fmaxf(v[i].x, v[i].y), fmaxf(v[i].z, v[i].w)));
#pragma unroll
    for (int o = 32; o; o >>= 1) m = fmaxf(m, __shfl_xor(m, o));
    if (lane == 0) red[wid] = m;
    __syncthreads();
    m = fmaxf(fmaxf(red[0], red[1]), fmaxf(red[2], red[3]));
    float s = 0.f;
#pragma unroll
    for (int i = 0; i < 4; ++i) {
        v[i].x = __expf(v[i].x - m); v[i].y = __expf(v[i].y - m);
        v[i].z = __expf(v[i].z - m); v[i].w = __expf(v[i].w - m);
        s += v[i].x + v[i].y + v[i].z + v[i].w;
    }
#pragma unroll
    for (int o = 32; o; o >>= 1) s += __shfl_xor(s, o);
    if (lane == 0) red[4 + wid] = s;
    __syncthreads();
    s = red[4] + red[5] + red[6] + red[7];
    const float inv = 1.f / s;
#pragma unroll
    for (int i = 0; i < 4; ++i) {
        v[i].x *= inv; v[i].y *= inv; v[i].z *= inv; v[i].w *= inv;
        ((float4*)p)[tid + 256 * i] = v[i];
    }
}

// u_mod = u * out_vec, elementwise
__global__ __launch_bounds__(256) void umod_kernel(
    const float* __restrict__ u, const float* __restrict__ ov, float* __restrict__ um)
{
    const int i = blockIdx.x * 256 + threadIdx.x;
    float4 a = ((const float4*)u)[i];
    float4 b = ((const float4*)ov)[i];
    float4 c;
    c.x = a.x * b.x; c.y = a.y * b.y; c.z = a.z * b.z; c.w = a.w * b.w;
    ((float4*)um)[i] = c;
}

// ---------------------------------------------------------------------------
// Persistent bidirectional LSTM, v5: register-resident weights, one barrier.
//  - 64 WGs (32/dir), NU_=16 units/WG. W_hh slice lives in 128 VGPRs/lane
//    (1 WG/CU, 4 waves, launch_bounds(256,1) -> up to 512 VGPR/wave; no LDS
//    weight stream: kills the 64KB/step LDS-pipe serialization of v4).
//  - Lane map: unit j = tid>>4, gate g = (tid>>2)&3, k-chunk c = tid&3
//    (128 k each). Matvec: 128 reg-FMAs vs LDS h (16-way same-addr broadcast,
//    chunk stride 132 keeps banks distinct). Reduce = 2 shfl_xor.
//  - Single __syncthreads/step: staged h is double-buffered by parity, so
//    the pre-compute barrier alone orders WAR (write sh[s&1] at step s vs
//    reads of sh[s&1] at step s-2 are separated by barrier s-1).
//  - Early publish: lane (g==0,c==0) of each unit stores its tagged slot
//    (step16<<16)|bf16(h) directly after computing h, before any barrier.
//  - Tag-exact polling (poison-proof); 2-parity safety as in v4.
// ---------------------------------------------------------------------------
#define NU_ 16   // hidden units per WG

__global__ __launch_bounds__(256, 1) void lstm_kernel(
    const float* __restrict__ whh_f, const float* __restrict__ whh_b,
    const float* __restrict__ xg_f, const float* __restrict__ xg_b,
    float* __restrict__ hf_out, float* __restrict__ hb_out,
    unsigned int* __restrict__ hbuf)   // [2 dirs][2 parity][512] 4B tagged
{
    __shared__ float sh[2][4 * 132];   // 4,224 B: parity x (4 chunks x 132)

    const int tid  = threadIdx.x;
    const int dir  = blockIdx.x >> 5;   // grid=64: 0..31 fwd, 32..63 bwd
    const int w    = blockIdx.x & 31;
    const int lane = tid & 63;
    const int j    = tid >> 4;          // unit 0..15
    const int g    = (tid >> 2) & 3;    // gate 0..3 (i,f,g,o)
    const int c    = tid & 3;           // k-chunk 0..3 (128 elems)
    const int lu   = lane >> 4;         // unit-in-wave 0..3
    const int u0   = w * NU_;

    const float* whh = dir ? whh_b : whh_f;
    const float* xg  = dir ? xg_b  : xg_f;
    float* hout = dir ? hb_out : hf_out;
    unsigned int* hb = hbuf + dir * 1024;

    // One-time: this lane's 128 W_hh weights into VGPRs.
    float wreg[128];
    {
        const float* wr = whh + (size_t)(g * E_ + u0 + j) * E_ + 128 * c;
#pragma unroll
        for (int i = 0; i < 32; ++i)
            *(float4*)&wreg[4 * i] = *(const float4*)(wr + 4 * i);
    }
    for (int i = tid; i < 2 * 4 * 132; i += 256) ((float*)sh)[i] = 0.f;

    float creg = 0.f;
    const float gsc  = (g == 2) ? 2.f : 1.f;
    const float gmul = (g == 2) ? 2.f : 1.f;
    const float gadd = (g == 2) ? -1.f : 0.f;

    float xv = xg[(size_t)(dir ? (T_ - 1) : 0) * G4_ + g * E_ + u0 + j];
    unsigned int budget = 1u << 23;    // hang guard; never hit when healthy

    const int e0 = 2 * tid;                        // slots 2t, 2t+1
    const int p0 = (e0 >> 7) * 132 + (e0 & 127);   // e0 even -> p1 = p0+1

    for (int s = 0; s < T_; ++s) {
        const int t = dir ? (T_ - 1 - s) : s;

        if (s > 0) {
            const unsigned int tt = (unsigned int)(s - 1) & 0xFFFFu;
            const unsigned long long* src =
                (const unsigned long long*)(hb + ((s - 1) & 1) * 512);
            unsigned long long v;
            for (;;) {
                v = __hip_atomic_load(src + tid, __ATOMIC_RELAXED,
                                      __HIP_MEMORY_SCOPE_AGENT);
                const unsigned int lo = (unsigned int)v;
                const unsigned int hi = (unsigned int)(v >> 32);
                if (((lo >> 16) == tt && (hi >> 16) == tt) || !--budget) break;
            }
            float2 hv;
            hv.x = __uint_as_float((unsigned int)v << 16);          // bf16->f32
            hv.y = __uint_as_float((unsigned int)(v >> 32) << 16);
            *(float2*)&sh[s & 1][p0] = hv;
        }
        __syncthreads();   // the only per-step barrier (orders staging + WAR)

        // matvec: 128 reg-weight FMAs against LDS h chunk
        const float* hc = &sh[s & 1][132 * c];
        float sum = 0.f;
#pragma unroll
        for (int i = 0; i < 32; ++i) {
            const float4 h4 = *(const float4*)&hc[4 * i];
            sum = fmaf(wreg[4 * i + 0], h4.x, sum);
            sum = fmaf(wreg[4 * i + 1], h4.y, sum);
            sum = fmaf(wreg[4 * i + 2], h4.z, sum);
            sum = fmaf(wreg[4 * i + 3], h4.w, sum);
        }
        // reduce across the 4 chunk-lanes
        sum += __shfl_xor(sum, 1);
        sum += __shfl_xor(sum, 2);

        // branchless gate: sig for i,f,o; tanh (=2*sig(2x)-1) for g
        const float xx = (sum + xv) * gsc;
        const float rr = __builtin_amdgcn_rcpf(1.f + __expf(-xx));
        const float val = fmaf(rr, gmul, gadd);

        // gather the 4 gates of this lane's unit (within-wave shuffles)
        const int base = 16 * lu + c;
        const float iv = __shfl(val, base);
        const float fv = __shfl(val, base + 4);
        const float gv = __shfl(val, base + 8);
        const float ov = __shfl(val, base + 12);
        creg = fmaf(fv, creg, iv * gv);      // redundant across the 16 unit-lanes
        const float th = fmaf(2.f, __builtin_amdgcn_rcpf(1.f + __expf(-2.f * creg)), -1.f);
        const float h = ov * th;

        // early publish: one lane per unit, pre-barrier
        if ((tid & 15) == 0) {
            const unsigned int ub = __float_as_uint(h);
            const unsigned int b16 = (ub + 0x7FFFu + ((ub >> 16) & 1u)) >> 16; // RNE
            const unsigned int pkt = (((unsigned int)s & 0xFFFFu) << 16) | b16;
            __hip_atomic_store(hb + (s & 1) * 512 + u0 + j, pkt,
                               __ATOMIC_RELAXED, __HIP_MEMORY_SCOPE_AGENT);
            hout[(size_t)t * E_ + u0 + j] = h;   // fp32 h for the projection
        }

        if (s + 1 < T_)
            xv = xg[(size_t)(dir ? (T_ - 2 - s) : (s + 1)) * G4_ + g * E_ + u0 + j];
    }
}

// score[t] = dot(hf[t], fw[0:512]) + dot(hb[t], fw[512:1024]) + fb
__global__ __launch_bounds__(256) void final_kernel(
    const float* __restrict__ hf, const float* __restrict__ hb,
    const float* __restrict__ fw, const float* __restrict__ fb,
    float* __restrict__ out)
{
    const int t = blockIdx.x * 4 + (threadIdx.x >> 6);
    const int lane = threadIdx.x & 63;
    float s = 0.f;
#pragma unroll
    for (int i = 0; i < 8; ++i) {
        const int e = lane + 64 * i;
        s += hf[(size_t)t * E_ + e] * fw[e];
    }
#pragma unroll
    for (int i = 0; i < 8; ++i) {
        const int e = lane + 64 * i;
        s += hb[(size_t)t * E_ + e] * fw[E_ + e];
    }
#pragma unroll
    for (int o = 32; o; o >>= 1) s += __shfl_xor(s, o);
    if (lane == 0) out[t] = s + fb[0];
}

// ---------------------------------------------------------------------------
// Workspace layout (floats; 1 MB = 262144 floats). Peak ~96 MB via overlays:
//   a [0,8MB) b [8,16) u [16,24) S [24,88) ov [88,96)
//   um [24,32)  xf [32,64)  xb [64,96)  hf [0,8)  hb [8,16)
//   tagged hbuf @96MB (2048 x 4B = 8KB)
// ---------------------------------------------------------------------------
extern "C" void kernel_launch(void* const* d_in, const int* in_sizes, int n_in,
                              void* d_out, int out_size, void* d_ws, size_t ws_size,
                              hipStream_t stream)
{
    const float* x     = (const float*)d_in[0];
    const float* Amat  = (const float*)d_in[1];
    const float* Bmat  = (const float*)d_in[2];
    const float* Umat  = (const float*)d_in[3];
    const float* wih_f = (const float*)d_in[4];
    const float* whh_f = (const float*)d_in[5];
    const float* bih_f = (const float*)d_in[6];
    const float* bhh_f = (const float*)d_in[7];
    const float* wih_b = (const float*)d_in[8];
    const float* whh_b = (const float*)d_in[9];
    const float* bih_b = (const float*)d_in[10];
    const float* bhh_b = (const float*)d_in[11];
    const float* fw    = (const float*)d_in[12];
    const float* fb    = (const float*)d_in[13];
    float* out = (float*)d_out;
    float* ws = (float*)d_ws;

    const size_t MBf = 262144;
    float* a_  = ws;
    float* b_  = ws + 8 * MBf;
    float* u_  = ws + 16 * MBf;
    float* S_  = ws + 24 * MBf;
    float* ov_ = ws + 88 * MBf;
    float* um_ = ws + 24 * MBf;
    float* xf_ = ws + 32 * MBf;
    float* xb_ = ws + 64 * MBf;
    float* hf_ = ws;
    float* hb_ = ws + 8 * MBf;
    unsigned int* hbuf_ = (unsigned int*)(ws + 96 * MBf);

    dim3 blk(256);

    gemm_kernel<<<dim3(4, 32), blk, 0, stream>>>(x, Amat, a_, T_, E_, IN_, 0, nullptr, nullptr);
    gemm_kernel<<<dim3(4, 32), blk, 0, stream>>>(x, Bmat, b_, T_, E_, IN_, 0, nullptr, nullptr);
    gemm_kernel<<<dim3(4, 32), blk, 0, stream>>>(x, Umat, u_, T_, E_, IN_, 0, nullptr, nullptr);
    gemm_kernel<<<dim3(32, 32), blk, 0, stream>>>(u_, a_, S_, T_, T_, E_, 1, nullptr, nullptr);
    softmax_kernel<<<dim3(T_), blk, 0, stream>>>(S_);
    gemm_kernel<<<dim3(4, 32), blk, 0, stream>>>(S_, b_, ov_, T_, E_, T_, 0, nullptr, nullptr);
    umod_kernel<<<dim3(2048), blk, 0, stream>>>(u_, ov_, um_);
    gemm_kernel<<<dim3(16, 32), blk, 0, stream>>>(um_, wih_f, xf_, T_, G4_, E_, 1, bih_f, bhh_f);
    gemm_kernel<<<dim3(16, 32), blk, 0, stream>>>(um_, wih_b, xb_, T_, G4_, E_, 1, bih_b, bhh_b);
    lstm_kernel<<<dim3(64), blk, 0, stream>>>(whh_f, whh_b, xf_, xb_, hf_, hb_, hbuf_);
    final_kernel<<<dim3(1024), blk, 0, stream>>>(hf_, hb_, fw, fb, out);
}

// Round 6
// 8148.095 us; speedup vs baseline: 1.7879x; 1.2184x over previous
//
#include <hip/hip_runtime.h>
#include <cstddef>
#include <cstdint>

// Problem dims (fixed)
#define T_   4096
#define IN_  1024
#define E_   512
#define G4_  2048   // 4*E

// ---------------------------------------------------------------------------
// fp32 tiled GEMM, 128x128 tile: C[M,N] = A[M,K] @ op(B) (+bias1+bias2)
// BT=0: B is [K,N].  BT=1: B is [N,K] (C = A @ B^T). 256 thr, 8x8/thread.
// ---------------------------------------------------------------------------
__global__ __launch_bounds__(256) void gemm_kernel(
    const float* __restrict__ A, const float* __restrict__ B, float* __restrict__ C,
    int M, int N, int K, int BT,
    const float* __restrict__ bias1, const float* __restrict__ bias2)
{
    __shared__ float As[16][128];
    __shared__ float Bs[16][132];
    const int tid = threadIdx.x;
    const int bm = blockIdx.y * 128;
    const int bn = blockIdx.x * 128;
    const int tx = tid & 15;
    const int ty = tid >> 4;
    const int lr = tid >> 1;
    const int lc = (tid & 1) * 8;
    const int bkk = tid & 15;
    const int bn0 = (tid >> 4) * 8;

    float acc[8][8];
#pragma unroll
    for (int i = 0; i < 8; ++i)
#pragma unroll
        for (int j = 0; j < 8; ++j) acc[i][j] = 0.f;

    for (int k0 = 0; k0 < K; k0 += 16) {
        float av[8], bv[8];
        {
            const float* ap = A + (size_t)(bm + lr) * K + (k0 + lc);
            *(float4*)&av[0] = *(const float4*)ap;
            *(float4*)&av[4] = *(const float4*)(ap + 4);
        }
        if (BT) {
            const float* bp = B + (size_t)(bn + lr) * K + (k0 + lc);
            *(float4*)&bv[0] = *(const float4*)bp;
            *(float4*)&bv[4] = *(const float4*)(bp + 4);
        } else {
            const float* bp = B + (size_t)(k0 + bkk) * N + (bn + bn0);
            *(float4*)&bv[0] = *(const float4*)bp;
            *(float4*)&bv[4] = *(const float4*)(bp + 4);
        }
        __syncthreads();
#pragma unroll
        for (int i = 0; i < 8; ++i) As[lc + i][lr] = av[i];
        if (BT) {
#pragma unroll
            for (int i = 0; i < 8; ++i) Bs[lc + i][lr] = bv[i];
        } else {
#pragma unroll
            for (int j = 0; j < 8; ++j) Bs[bkk][bn0 + j] = bv[j];
        }
        __syncthreads();
#pragma unroll
        for (int kk = 0; kk < 16; ++kk) {
            float a0[8], b0[8];
            *(float4*)&a0[0] = *(const float4*)&As[kk][ty * 8];
            *(float4*)&a0[4] = *(const float4*)&As[kk][ty * 8 + 4];
            *(float4*)&b0[0] = *(const float4*)&Bs[kk][tx * 8];
            *(float4*)&b0[4] = *(const float4*)&Bs[kk][tx * 8 + 4];
#pragma unroll
            for (int i = 0; i < 8; ++i)
#pragma unroll
                for (int j = 0; j < 8; ++j)
                    acc[i][j] = fmaf(a0[i], b0[j], acc[i][j]);
        }
    }

    float bias[8];
#pragma unroll
    for (int j = 0; j < 8; ++j) bias[j] = 0.f;
    if (bias1) {
#pragma unroll
        for (int j = 0; j < 8; ++j) bias[j] += bias1[bn + tx * 8 + j];
    }
    if (bias2) {
#pragma unroll
        for (int j = 0; j < 8; ++j) bias[j] += bias2[bn + tx * 8 + j];
    }
#pragma unroll
    for (int i = 0; i < 8; ++i) {
        float outv[8];
#pragma unroll
        for (int j = 0; j < 8; ++j) outv[j] = acc[i][j] + bias[j];
        float* cp = C + (size_t)(bm + ty * 8 + i) * N + (bn + tx * 8);
        *(float4*)cp = *(float4*)&outv[0];
        *(float4*)(cp + 4) = *(float4*)&outv[4];
    }
}

// ---------------------------------------------------------------------------
// fp32 tiled GEMM, 64x128 tile (2x the blocks of the 128-tile: fills all 256
// CUs when M=4096,N=512 -> grid 256). 256 thr, 4x8/thread. BT=0 only callers.
// ---------------------------------------------------------------------------
__global__ __launch_bounds__(256) void gemm64_kernel(
    const float* __restrict__ A, const float* __restrict__ B, float* __restrict__ C,
    int M, int N, int K, int BT)
{
    __shared__ float As[16][68];   // pad 68: write conflicts drop to free 2-way
    __shared__ float Bs[16][132];
    const int tid = threadIdx.x;
    const int bm = blockIdx.y * 64;
    const int bn = blockIdx.x * 128;
    const int tx = tid & 15;
    const int ty = tid >> 4;
    const int alr = tid >> 2;          // A loader row 0..63
    const int alc = (tid & 3) * 4;     // A loader k-offset {0,4,8,12}
    const int blr = tid >> 1;          // B loader row (BT)
    const int blc = (tid & 1) * 8;
    const int bkk = tid & 15;          // B loader k (non-BT)
    const int bn0 = (tid >> 4) * 8;

    float acc[4][8];
#pragma unroll
    for (int i = 0; i < 4; ++i)
#pragma unroll
        for (int j = 0; j < 8; ++j) acc[i][j] = 0.f;

    for (int k0 = 0; k0 < K; k0 += 16) {
        float av[4], bv[8];
        *(float4*)&av[0] = *(const float4*)(A + (size_t)(bm + alr) * K + (k0 + alc));
        if (BT) {
            const float* bp = B + (size_t)(bn + blr) * K + (k0 + blc);
            *(float4*)&bv[0] = *(const float4*)bp;
            *(float4*)&bv[4] = *(const float4*)(bp + 4);
        } else {
            const float* bp = B + (size_t)(k0 + bkk) * N + (bn + bn0);
            *(float4*)&bv[0] = *(const float4*)bp;
            *(float4*)&bv[4] = *(const float4*)(bp + 4);
        }
        __syncthreads();
#pragma unroll
        for (int i = 0; i < 4; ++i) As[alc + i][alr] = av[i];
        if (BT) {
#pragma unroll
            for (int i = 0; i < 8; ++i) Bs[blc + i][blr] = bv[i];
        } else {
#pragma unroll
            for (int j = 0; j < 8; ++j) Bs[bkk][bn0 + j] = bv[j];
        }
        __syncthreads();
#pragma unroll
        for (int kk = 0; kk < 16; ++kk) {
            float4 a0 = *(const float4*)&As[kk][ty * 4];
            float b0[8];
            *(float4*)&b0[0] = *(const float4*)&Bs[kk][tx * 8];
            *(float4*)&b0[4] = *(const float4*)&Bs[kk][tx * 8 + 4];
            const float am[4] = {a0.x, a0.y, a0.z, a0.w};
#pragma unroll
            for (int i = 0; i < 4; ++i)
#pragma unroll
                for (int j = 0; j < 8; ++j)
                    acc[i][j] = fmaf(am[i], b0[j], acc[i][j]);
        }
    }

#pragma unroll
    for (int i = 0; i < 4; ++i) {
        float* cp = C + (size_t)(bm + ty * 4 + i) * N + (bn + tx * 8);
        *(float4*)cp = *(float4*)&acc[i][0];
        *(float4*)(cp + 4) = *(float4*)&acc[i][4];
    }
}

// ---------------------------------------------------------------------------
// Row softmax over 4096 columns, in place. One block per row.
// ---------------------------------------------------------------------------
__global__ __launch_bounds__(256) void softmax_kernel(float* __restrict__ S)
{
    __shared__ float red[8];
    float* p = S + (size_t)blockIdx.x * T_;
    const int tid = threadIdx.x;
    const int wid = tid >> 6;
    const int lane = tid & 63;
    float4 v[4];
#pragma unroll
    for (int i = 0; i < 4; ++i) v[i] = ((const float4*)p)[tid + 256 * i];
    float m = -3.0e38f;
#pragma unroll
    for (int i = 0; i < 4; ++i)
        m = fmaxf(m, fmaxf(fmaxf(v[i].x, v[i].y), fmaxf(v[i].z, v[i].w)));
#pragma unroll
    for (int o = 32; o; o >>= 1) m = fmaxf(m, __shfl_xor(m, o));
    if (lane == 0) red[wid] = m;
    __syncthreads();
    m = fmaxf(fmaxf(red[0], red[1]), fmaxf(red[2], red[3]));
    float s = 0.f;
#pragma unroll
    for (int i = 0; i < 4; ++i) {
        v[i].x = __expf(v[i].x - m); v[i].y = __expf(v[i].y - m);
        v[i].z = __expf(v[i].z - m); v[i].w = __expf(v[i].w - m);
        s += v[i].x + v[i].y + v[i].z + v[i].w;
    }
#pragma unroll
    for (int o = 32; o; o >>= 1) s += __shfl_xor(s, o);
    if (lane == 0) red[4 + wid] = s;
    __syncthreads();
    s = red[4] + red[5] + red[6] + red[7];
    const float inv = 1.f / s;
#pragma unroll
    for (int i = 0; i < 4; ++i) {
        v[i].x *= inv; v[i].y *= inv; v[i].z *= inv; v[i].w *= inv;
        ((float4*)p)[tid + 256 * i] = v[i];
    }
}

// u_mod = u * out_vec, elementwise
__global__ __launch_bounds__(256) void umod_kernel(
    const float* __restrict__ u, const float* __restrict__ ov, float* __restrict__ um)
{
    const int i = blockIdx.x * 256 + threadIdx.x;
    float4 a = ((const float4*)u)[i];
    float4 b = ((const float4*)ov)[i];
    float4 c;
    c.x = a.x * b.x; c.y = a.y * b.y; c.z = a.z * b.z; c.w = a.w * b.w;
    ((float4*)um)[i] = c;
}

// ---------------------------------------------------------------------------
// Persistent bidirectional LSTM, v6 = v5 + paced polling + 4-acc matvec.
//  - Paced poll: all WGs publish step s at ~the same wall time. Instead of
//    sampling immediately (guaranteed miss -> wasted RT), spin on
//    s_memrealtime (100 MHz, wave-uniform) until ~250ns after our own
//    publish, then sample: detect ~= visibility + 1 poll RT. If we arrive
//    late the delay condition is already satisfied (zero cost).
//  - 4 accumulators (x/y/z/w) break the 128-deep dependent FMA chain.
// Everything else identical to v5 (W_hh in VGPRs, 64 WGs, tagged 4B slots,
// parity double-buffer, single barrier, early publish).
// ---------------------------------------------------------------------------
#define NU_ 16          // hidden units per WG
#define PACE_TICKS 25L  // ~250 ns at the 100 MHz realtime clock

__global__ __launch_bounds__(256, 1) void lstm_kernel(
    const float* __restrict__ whh_f, const float* __restrict__ whh_b,
    const float* __restrict__ xg_f, const float* __restrict__ xg_b,
    float* __restrict__ hf_out, float* __restrict__ hb_out,
    unsigned int* __restrict__ hbuf)   // [2 dirs][2 parity][512] 4B tagged
{
    __shared__ float sh[2][4 * 132];   // parity x (4 chunks x 132)

    const int tid  = threadIdx.x;
    const int dir  = blockIdx.x >> 5;   // grid=64: 0..31 fwd, 32..63 bwd
    const int w    = blockIdx.x & 31;
    const int lane = tid & 63;
    const int j    = tid >> 4;          // unit 0..15
    const int g    = (tid >> 2) & 3;    // gate 0..3 (i,f,g,o)
    const int c    = tid & 3;           // k-chunk 0..3 (128 elems)
    const int lu   = lane >> 4;         // unit-in-wave 0..3
    const int u0   = w * NU_;

    const float* whh = dir ? whh_b : whh_f;
    const float* xg  = dir ? xg_b  : xg_f;
    float* hout = dir ? hb_out : hf_out;
    unsigned int* hb = hbuf + dir * 1024;

    // One-time: this lane's 128 W_hh weights into VGPRs.
    float wreg[128];
    {
        const float* wr = whh + (size_t)(g * E_ + u0 + j) * E_ + 128 * c;
#pragma unroll
        for (int i = 0; i < 32; ++i)
            *(float4*)&wreg[4 * i] = *(const float4*)(wr + 4 * i);
    }
    for (int i = tid; i < 2 * 4 * 132; i += 256) ((float*)sh)[i] = 0.f;

    float creg = 0.f;
    const float gsc  = (g == 2) ? 2.f : 1.f;
    const float gmul = (g == 2) ? 2.f : 1.f;
    const float gadd = (g == 2) ? -1.f : 0.f;

    float xv = xg[(size_t)(dir ? (T_ - 1) : 0) * G4_ + g * E_ + u0 + j];
    unsigned int budget = 1u << 23;    // hang guard; never hit when healthy

    const int e0 = 2 * tid;                        // slots 2t, 2t+1
    const int p0 = (e0 >> 7) * 132 + (e0 & 127);   // e0 even -> p1 = p0+1

    long long tpub = (long long)__builtin_amdgcn_s_memrealtime();

    for (int s = 0; s < T_; ++s) {
        const int t = dir ? (T_ - 1 - s) : s;

        if (s > 0) {
            // pace: don't sample before stores can plausibly be visible
            while ((long long)__builtin_amdgcn_s_memrealtime() - tpub < PACE_TICKS) {}
            const unsigned int tt = (unsigned int)(s - 1) & 0xFFFFu;
            const unsigned long long* src =
                (const unsigned long long*)(hb + ((s - 1) & 1) * 512);
            unsigned long long v;
            for (;;) {
                v = __hip_atomic_load(src + tid, __ATOMIC_RELAXED,
                                      __HIP_MEMORY_SCOPE_AGENT);
                const unsigned int lo = (unsigned int)v;
                const unsigned int hi = (unsigned int)(v >> 32);
                if (((lo >> 16) == tt && (hi >> 16) == tt) || !--budget) break;
            }
            float2 hv;
            hv.x = __uint_as_float((unsigned int)v << 16);          // bf16->f32
            hv.y = __uint_as_float((unsigned int)(v >> 32) << 16);
            *(float2*)&sh[s & 1][p0] = hv;
        }
        __syncthreads();   // the only per-step barrier

        // matvec: 128 reg-weight FMAs, 4 independent accumulators
        const float* hc = &sh[s & 1][132 * c];
        float sx = 0.f, sy = 0.f, sz = 0.f, sw = 0.f;
#pragma unroll
        for (int i = 0; i < 32; ++i) {
            const float4 h4 = *(const float4*)&hc[4 * i];
            sx = fmaf(wreg[4 * i + 0], h4.x, sx);
            sy = fmaf(wreg[4 * i + 1], h4.y, sy);
            sz = fmaf(wreg[4 * i + 2], h4.z, sz);
            sw = fmaf(wreg[4 * i + 3], h4.w, sw);
        }
        float sum = (sx + sy) + (sz + sw);
        // reduce across the 4 chunk-lanes
        sum += __shfl_xor(sum, 1);
        sum += __shfl_xor(sum, 2);

        // branchless gate: sig for i,f,o; tanh (=2*sig(2x)-1) for g
        const float xx = (sum + xv) * gsc;
        const float rr = __builtin_amdgcn_rcpf(1.f + __expf(-xx));
        const float val = fmaf(rr, gmul, gadd);

        // gather the 4 gates of this lane's unit (within-wave shuffles)
        const int base = 16 * lu + c;
        const float iv = __shfl(val, base);
        const float fv = __shfl(val, base + 4);
        const float gv = __shfl(val, base + 8);
        const float ov = __shfl(val, base + 12);
        creg = fmaf(fv, creg, iv * gv);      // redundant across the 16 unit-lanes
        const float th = fmaf(2.f, __builtin_amdgcn_rcpf(1.f + __expf(-2.f * creg)), -1.f);
        const float h = ov * th;

        // early publish: one lane per unit, pre-barrier
        if ((tid & 15) == 0) {
            const unsigned int ub = __float_as_uint(h);
            const unsigned int b16 = (ub + 0x7FFFu + ((ub >> 16) & 1u)) >> 16; // RNE
            const unsigned int pkt = (((unsigned int)s & 0xFFFFu) << 16) | b16;
            __hip_atomic_store(hb + (s & 1) * 512 + u0 + j, pkt,
                               __ATOMIC_RELAXED, __HIP_MEMORY_SCOPE_AGENT);
            hout[(size_t)t * E_ + u0 + j] = h;   // fp32 h for the projection
        }
        tpub = (long long)__builtin_amdgcn_s_memrealtime();

        if (s + 1 < T_)
            xv = xg[(size_t)(dir ? (T_ - 2 - s) : (s + 1)) * G4_ + g * E_ + u0 + j];
    }
}

// score[t] = dot(hf[t], fw[0:512]) + dot(hb[t], fw[512:1024]) + fb
__global__ __launch_bounds__(256) void final_kernel(
    const float* __restrict__ hf, const float* __restrict__ hb,
    const float* __restrict__ fw, const float* __restrict__ fb,
    float* __restrict__ out)
{
    const int t = blockIdx.x * 4 + (threadIdx.x >> 6);
    const int lane = threadIdx.x & 63;
    float s = 0.f;
#pragma unroll
    for (int i = 0; i < 8; ++i) {
        const int e = lane + 64 * i;
        s += hf[(size_t)t * E_ + e] * fw[e];
    }
#pragma unroll
    for (int i = 0; i < 8; ++i) {
        const int e = lane + 64 * i;
        s += hb[(size_t)t * E_ + e] * fw[E_ + e];
    }
#pragma unroll
    for (int o = 32; o; o >>= 1) s += __shfl_xor(s, o);
    if (lane == 0) out[t] = s + fb[0];
}

// ---------------------------------------------------------------------------
// Workspace layout (floats; 1 MB = 262144 floats). Peak ~96 MB via overlays:
//   a [0,8MB) b [8,16) u [16,24) S [24,88) ov [88,96)
//   um [24,32)  xf [32,64)  xb [64,96)  hf [0,8)  hb [8,16)
//   tagged hbuf @96MB (2048 x 4B = 8KB)
// ---------------------------------------------------------------------------
extern "C" void kernel_launch(void* const* d_in, const int* in_sizes, int n_in,
                              void* d_out, int out_size, void* d_ws, size_t ws_size,
                              hipStream_t stream)
{
    const float* x     = (const float*)d_in[0];
    const float* Amat  = (const float*)d_in[1];
    const float* Bmat  = (const float*)d_in[2];
    const float* Umat  = (const float*)d_in[3];
    const float* wih_f = (const float*)d_in[4];
    const float* whh_f = (const float*)d_in[5];
    const float* bih_f = (const float*)d_in[6];
    const float* bhh_f = (const float*)d_in[7];
    const float* wih_b = (const float*)d_in[8];
    const float* whh_b = (const float*)d_in[9];
    const float* bih_b = (const float*)d_in[10];
    const float* bhh_b = (const float*)d_in[11];
    const float* fw    = (const float*)d_in[12];
    const float* fb    = (const float*)d_in[13];
    float* out = (float*)d_out;
    float* ws = (float*)d_ws;

    const size_t MBf = 262144;
    float* a_  = ws;
    float* b_  = ws + 8 * MBf;
    float* u_  = ws + 16 * MBf;
    float* S_  = ws + 24 * MBf;
    float* ov_ = ws + 88 * MBf;
    float* um_ = ws + 24 * MBf;
    float* xf_ = ws + 32 * MBf;
    float* xb_ = ws + 64 * MBf;
    float* hf_ = ws;
    float* hb_ = ws + 8 * MBf;
    unsigned int* hbuf_ = (unsigned int*)(ws + 96 * MBf);

    dim3 blk(256);

    // a, b, u = x @ {A,B,U}: 64x128 tiles -> grid 256 (full GPU per launch)
    gemm64_kernel<<<dim3(4, 64), blk, 0, stream>>>(x, Amat, a_, T_, E_, IN_, 0);
    gemm64_kernel<<<dim3(4, 64), blk, 0, stream>>>(x, Bmat, b_, T_, E_, IN_, 0);
    gemm64_kernel<<<dim3(4, 64), blk, 0, stream>>>(x, Umat, u_, T_, E_, IN_, 0);
    gemm_kernel<<<dim3(32, 32), blk, 0, stream>>>(u_, a_, S_, T_, T_, E_, 1, nullptr, nullptr);
    softmax_kernel<<<dim3(T_), blk, 0, stream>>>(S_);
    gemm64_kernel<<<dim3(4, 64), blk, 0, stream>>>(S_, b_, ov_, T_, E_, T_, 0);
    umod_kernel<<<dim3(2048), blk, 0, stream>>>(u_, ov_, um_);
    gemm_kernel<<<dim3(16, 32), blk, 0, stream>>>(um_, wih_f, xf_, T_, G4_, E_, 1, bih_f, bhh_f);
    gemm_kernel<<<dim3(16, 32), blk, 0, stream>>>(um_, wih_b, xb_, T_, G4_, E_, 1, bih_b, bhh_b);
    lstm_kernel<<<dim3(64), blk, 0, stream>>>(whh_f, whh_b, xf_, xb_, hf_, hb_, hbuf_);
    final_kernel<<<dim3(1024), blk, 0, stream>>>(hf_, hb_, fw, fb, out);
}